// Round 9
// baseline (464.365 us; speedup 1.0000x reference)
//
#include <hip/hip_runtime.h>
#include <math.h>

#define N_TOK 131072
#define DIM   64
#define QS    8
#define KS    1024

typedef _Float16 f16x8 __attribute__((ext_vector_type(8)));
typedef float    f32x4 __attribute__((ext_vector_type(4)));

#define RSCALE   2048.0f
#define RISCALE  4.8828125e-4f   // 2^-11

// split fp32 v into f16 limbs + scaled-hi: v ~= hi + lo*2^-11 ; hs = 2048*hi (exact)
#define SPLIT3(v, hi, lo, hs) { _Float16 _h = (_Float16)(v); (hi) = _h;        \
                                (lo) = (_Float16)(((v) - (float)_h) * RSCALE); \
                                (hs) = (_Float16)((float)_h * RSCALE); }

// ---- workspace layout G: 256 MINI-chunks, each 8448 B:
//   [0   .. 8191]  frag limbs: 8 sub-slots of 1KB (2 groups x {h0,h1,l0,l1})
//   [8192.. 8319]  32 floats: -1024*||c||^2 seeds for the mini's 32 codewords
//   [8320.. 8447]  pad (staged but unused; width-4 LDS load covers 256B)
// Mini c covers stage q = c>>5, codewords (c&31)*32 .. +31.
#define MINI_B 8448
#define MINI_H 4224     // _Float16 elements per mini
#define SEED_H 4096     // half-offset of seed region (byte 8192)

// ---- pre-pass 1: codebook -> f16 limbs in MFMA fragment order.
// slot s = (q*64+g)*4 + l*2 + h ; mini = s>>3, sub = s&7.
__global__ void conv_kernel(const float* __restrict__ cb, _Float16* __restrict__ G) {
    int t = blockIdx.x * blockDim.x + threadIdx.x;
    if (t >= 2048 * 64) return;
    const int lane = t & 63, slot = t >> 6;
    const int h = slot & 1, l = (slot >> 1) & 1, g = (slot >> 2) & 63, q = slot >> 8;
    const int cw = g * 16 + (lane & 15);
    const int d0 = h * 32 + (lane >> 4) * 8;
    const float* src = cb + ((size_t)q * KS + cw) * DIM + d0;
    f16x8 v;
#pragma unroll
    for (int j = 0; j < 8; ++j) {
        float c = src[j];
        _Float16 hi = (_Float16)c;
        v[j] = (l == 0) ? hi : (_Float16)((c - (float)hi) * RSCALE);
    }
    const int c = slot >> 3, w = slot & 7;
    *(f16x8*)(G + (size_t)c * MINI_H + w * 512 + lane * 8) = v;
}

// ---- pre-pass 2: dc2 seeds written into each mini's tail ----
__global__ void dc2_kernel(const float* __restrict__ cb, float* __restrict__ Gf) {
    int i = blockIdx.x * blockDim.x + threadIdx.x;
    if (i < QS * KS) {
        const float* c = cb + (size_t)i * DIM;
        float s = 0.f;
#pragma unroll
        for (int d = 0; d < DIM; ++d) s = fmaf(c[d], c[d], s);
        const int q = i >> 10, k = i & 1023;
        const int ch = q * 32 + (k >> 5), j = k & 31;
        Gf[(size_t)ch * (MINI_B / 4) + (SEED_H / 2) + j] = -1024.0f * s;
    }
}

// ---- main: BARRIER-FREE single-wave blocks. 2048 blocks x 64 threads; each
// wave owns 64 tokens (4 sets, r6 reuse preserved) and a private 2x8.4KB LDS
// double buffer (8 blocks/CU = 135KB). Staging sync = counted s_waitcnt
// vmcnt(9) (T4): issue next mini's 9 global_load_lds, wait until only those 9
// remain -> previous mini resident. No __syncthreads anywhere; the 8 waves/CU
// drift freely and fill each other's MFMA gaps.
__global__ __launch_bounds__(64, 2)
void rvq_mfma_kernel(const float* __restrict__ x,
                     const float* __restrict__ cbf,
                     const _Float16* __restrict__ F,
                     float* __restrict__ out) {
    __shared__ __attribute__((aligned(16))) _Float16 smem[2 * MINI_H]; // 16896 B

    const int lane = threadIdx.x;
    const int quad = lane >> 4;
    const int m    = lane & 15;
    const int quad4 = quad * 4;

    const int tokenBase = blockIdx.x * 64;

    // token limbs, 4 sets (B-frag layout): th = hi, tl = 2048*(r-hi), ts = 2048*hi
    f16x8 th00, th01, tl00, tl01, ts00, ts01;
    f16x8 th10, th11, tl10, tl11, ts10, ts11;
    f16x8 th20, th21, tl20, tl21, ts20, ts21;
    f16x8 th30, th31, tl30, tl31, ts30, ts31;

#define LOADTOK(S, TH0, TH1, TL0, TL1, TS0, TS1) {                                \
        const float* xa = x + (size_t)(tokenBase + (S) * 16 + m) * DIM + quad * 8;\
        f32x4 a0 = __builtin_nontemporal_load((const f32x4*)(xa));                \
        f32x4 a1 = __builtin_nontemporal_load((const f32x4*)(xa + 4));            \
        f32x4 a2 = __builtin_nontemporal_load((const f32x4*)(xa + 32));           \
        f32x4 a3 = __builtin_nontemporal_load((const f32x4*)(xa + 36));           \
        _Pragma("unroll")                                                         \
        for (int j = 0; j < 4; ++j) {                                             \
            SPLIT3(a0[j], TH0[j],   TL0[j],   TS0[j]);                            \
            SPLIT3(a1[j], TH0[j+4], TL0[j+4], TS0[j+4]);                          \
            SPLIT3(a2[j], TH1[j],   TL1[j],   TS1[j]);                            \
            SPLIT3(a3[j], TH1[j+4], TL1[j+4], TS1[j+4]);                          \
        }                                                                         \
    }
    LOADTOK(0, th00, th01, tl00, tl01, ts00, ts01);
    LOADTOK(1, th10, th11, tl10, tl11, ts10, ts11);
    LOADTOK(2, th20, th21, tl20, tl21, ts20, ts21);
    LOADTOK(3, th30, th31, tl30, tl31, ts30, ts31);

// stage one mini (8KB frags + 256B seed region) into LDS buffer BUF.
// 9 vmem ops total; single wave covers everything (no wave guard).
#define STAGE(GC, BUF) {                                                          \
        const char* _gs = (const char*)F + (size_t)(GC) * MINI_B + (lane << 4);   \
        _Float16* _ld = smem + (BUF) * MINI_H;                                    \
        _Pragma("unroll")                                                         \
        for (int _j = 0; _j < 8; ++_j)                                            \
            __builtin_amdgcn_global_load_lds(                                     \
                (const __attribute__((address_space(1))) void*)(_gs + _j * 1024), \
                (__attribute__((address_space(3))) void*)(_ld + _j * 512),        \
                16, 0, 0);                                                        \
        __builtin_amdgcn_global_load_lds(                                         \
            (const __attribute__((address_space(1))) void*)((const char*)F        \
                + (size_t)(GC) * MINI_B + 8192 + (lane << 2)),                    \
            (__attribute__((address_space(3))) void*)(smem + (BUF) * MINI_H       \
                                                      + SEED_H),                  \
            4, 0, 0);                                                             \
    }

// One group: 24 MFMAs = 4 independent depth-6 chains (one per token-set),
// all sharing the same codeword fragments. acc IS the scaled score.
#define COMPUTE(CH0, CH1, CL0, CL1, CIV, G) {                                       \
        __builtin_amdgcn_s_setprio(1);                                              \
        f32x4 A0 = __builtin_amdgcn_mfma_f32_16x16x32_f16(CH0, ts00, CIV, 0,0,0);   \
        f32x4 A1 = __builtin_amdgcn_mfma_f32_16x16x32_f16(CH0, ts10, CIV, 0,0,0);   \
        f32x4 A2 = __builtin_amdgcn_mfma_f32_16x16x32_f16(CH0, ts20, CIV, 0,0,0);   \
        f32x4 A3 = __builtin_amdgcn_mfma_f32_16x16x32_f16(CH0, ts30, CIV, 0,0,0);   \
        A0 = __builtin_amdgcn_mfma_f32_16x16x32_f16(CH1, ts01, A0, 0,0,0);          \
        A1 = __builtin_amdgcn_mfma_f32_16x16x32_f16(CH1, ts11, A1, 0,0,0);          \
        A2 = __builtin_amdgcn_mfma_f32_16x16x32_f16(CH1, ts21, A2, 0,0,0);          \
        A3 = __builtin_amdgcn_mfma_f32_16x16x32_f16(CH1, ts31, A3, 0,0,0);          \
        A0 = __builtin_amdgcn_mfma_f32_16x16x32_f16(CL0, th00, A0, 0,0,0);          \
        A1 = __builtin_amdgcn_mfma_f32_16x16x32_f16(CL0, th10, A1, 0,0,0);          \
        A2 = __builtin_amdgcn_mfma_f32_16x16x32_f16(CL0, th20, A2, 0,0,0);          \
        A3 = __builtin_amdgcn_mfma_f32_16x16x32_f16(CL0, th30, A3, 0,0,0);          \
        A0 = __builtin_amdgcn_mfma_f32_16x16x32_f16(CL1, th01, A0, 0,0,0);          \
        A1 = __builtin_amdgcn_mfma_f32_16x16x32_f16(CL1, th11, A1, 0,0,0);          \
        A2 = __builtin_amdgcn_mfma_f32_16x16x32_f16(CL1, th21, A2, 0,0,0);          \
        A3 = __builtin_amdgcn_mfma_f32_16x16x32_f16(CL1, th31, A3, 0,0,0);          \
        A0 = __builtin_amdgcn_mfma_f32_16x16x32_f16(CH0, tl00, A0, 0,0,0);          \
        A1 = __builtin_amdgcn_mfma_f32_16x16x32_f16(CH0, tl10, A1, 0,0,0);          \
        A2 = __builtin_amdgcn_mfma_f32_16x16x32_f16(CH0, tl20, A2, 0,0,0);          \
        A3 = __builtin_amdgcn_mfma_f32_16x16x32_f16(CH0, tl30, A3, 0,0,0);          \
        A0 = __builtin_amdgcn_mfma_f32_16x16x32_f16(CH1, tl01, A0, 0,0,0);          \
        A1 = __builtin_amdgcn_mfma_f32_16x16x32_f16(CH1, tl11, A1, 0,0,0);          \
        A2 = __builtin_amdgcn_mfma_f32_16x16x32_f16(CH1, tl21, A2, 0,0,0);          \
        A3 = __builtin_amdgcn_mfma_f32_16x16x32_f16(CH1, tl31, A3, 0,0,0);          \
        __builtin_amdgcn_s_setprio(0);                                              \
        const int base = (G) * 16 + quad4;                                          \
        _Pragma("unroll")                                                           \
        for (int i = 0; i < 4; ++i) {                                               \
            if (A0[i] > bv0) { bv0 = A0[i]; bi0 = base + i; }                       \
            if (A1[i] > bv1) { bv1 = A1[i]; bi1 = base + i; }                       \
            if (A2[i] > bv2) { bv2 = A2[i]; bi2 = base + i; }                       \
            if (A3[i] > bv3) { bv3 = A3[i]; bi3 = base + i; }                       \
        }                                                                           \
    }

    // prologue: stage mini 0 into buffer 0 (wait happens in first iteration)
    STAGE(0, 0);
    int cur = 0;

    for (int q = 0; q < QS; ++q) {
        const float* cfq = cbf + (size_t)q * KS * DIM;

        float bv0 = -INFINITY, bv1 = -INFINITY, bv2 = -INFINITY, bv3 = -INFINITY;
        int   bi0 = 0, bi1 = 0, bi2 = 0, bi3 = 0;

        for (int t = 0; t < 32; ++t) {
            const int gc = (q << 5) | t;
            if (gc + 1 < 256) {
                STAGE(gc + 1, cur ^ 1);   // prefetch next mini (9 vmem ops)
                // wait until only the 9 just-issued remain -> mini gc resident.
                // (any older epilogue stores/loads drain first; FIFO-safe)
                asm volatile("s_waitcnt vmcnt(9)" ::: "memory");
            } else {
                asm volatile("s_waitcnt vmcnt(0)" ::: "memory");
            }
            __builtin_amdgcn_sched_barrier(0);

            const _Float16* L   = smem + cur * MINI_H + lane * 8;
            const float*    dcL = (const float*)(smem + cur * MINI_H + SEED_H);

            f32x4 ci0 = *(const f32x4*)(dcL + quad4);
            f32x4 ci1 = *(const f32x4*)(dcL + 16 + quad4);

            f16x8 g0h0 = *(const f16x8*)(L);
            f16x8 g0h1 = *(const f16x8*)(L + 512);
            f16x8 g0l0 = *(const f16x8*)(L + 1024);
            f16x8 g0l1 = *(const f16x8*)(L + 1536);

            f16x8 g1h0 = *(const f16x8*)(L + 2048);
            f16x8 g1h1 = *(const f16x8*)(L + 2560);
            f16x8 g1l0 = *(const f16x8*)(L + 3072);
            f16x8 g1l1 = *(const f16x8*)(L + 3584);

            COMPUTE(g0h0, g0h1, g0l0, g0l1, ci0, t * 2 + 0);
            COMPUTE(g1h0, g1h1, g1l0, g1l1, ci1, t * 2 + 1);

            cur ^= 1;
        }

        // reduce over the 4 quad-lanes holding the same token (disjoint codewords):
        // 2 shuffle steps. Tie-break: lowest index, matching jnp.argmin.
#define REDUCE(BV, BI) {                                                          \
        _Pragma("unroll")                                                         \
        for (int mask = 16; mask <= 32; mask <<= 1) {                             \
            float ov = __shfl_xor(BV, mask, 64);                                  \
            int   oi = __shfl_xor(BI, mask, 64);                                  \
            if (ov > BV || (ov == BV && oi < BI)) { BV = ov; BI = oi; }           \
        }                                                                         \
    }
        REDUCE(bv0, bi0); REDUCE(bv1, bi1); REDUCE(bv2, bi2); REDUCE(bv3, bi3);

        // index writes: quad s writes set s's token (64 lanes = 64 tokens)
        {
            const int myTok = tokenBase + quad * 16 + m;
            const int mybi  = (quad == 0) ? bi0 : (quad == 1) ? bi1
                            : (quad == 2) ? bi2 : bi3;
            out[(size_t)N_TOK * DIM + (size_t)myTok * QS + q] = (float)mybi;
        }

        // residual update per set: reconstruct r, subtract fp32 codeword, re-split
        float ls = 0.f;
#define RESID(BI, TH0, TH1, TL0, TL1, TS0, TS1) {                                 \
        const float* cp = cfq + (size_t)(BI) * DIM + quad * 8;                    \
        f32x4 c0 = *(const f32x4*)(cp);                                           \
        f32x4 c1 = *(const f32x4*)(cp + 4);                                       \
        f32x4 c2 = *(const f32x4*)(cp + 32);                                      \
        f32x4 c3 = *(const f32x4*)(cp + 36);                                      \
        _Pragma("unroll")                                                         \
        for (int j = 0; j < 4; ++j) {                                             \
            float v0 = fmaf(RISCALE, (float)TL0[j],   (float)TH0[j])   - c0[j];   \
            float v1 = fmaf(RISCALE, (float)TL0[j+4], (float)TH0[j+4]) - c1[j];   \
            float v2 = fmaf(RISCALE, (float)TL1[j],   (float)TH1[j])   - c2[j];   \
            float v3 = fmaf(RISCALE, (float)TL1[j+4], (float)TH1[j+4]) - c3[j];   \
            ls = fmaf(v0, v0, ls); ls = fmaf(v1, v1, ls);                         \
            ls = fmaf(v2, v2, ls); ls = fmaf(v3, v3, ls);                         \
            SPLIT3(v0, TH0[j],   TL0[j],   TS0[j]);                               \
            SPLIT3(v1, TH0[j+4], TL0[j+4], TS0[j+4]);                             \
            SPLIT3(v2, TH1[j],   TL1[j],   TS1[j]);                               \
            SPLIT3(v3, TH1[j+4], TL1[j+4], TS1[j+4]);                             \
        }                                                                         \
    }
        RESID(bi0, th00, th01, tl00, tl01, ts00, ts01);
        RESID(bi1, th10, th11, tl10, tl11, ts10, ts11);
        RESID(bi2, th20, th21, tl20, tl21, ts20, ts21);
        RESID(bi3, th30, th31, tl30, tl31, ts30, ts31);

#pragma unroll
        for (int mask = 1; mask <= 32; mask <<= 1) ls += __shfl_xor(ls, mask, 64);
        if (lane == 0)
            atomicAdd(out + (size_t)N_TOK * DIM + (size_t)N_TOK * QS + q,
                      ls * (1.0f / ((float)N_TOK * (float)DIM)));
    }

    // xq = x - r_final (reconstruct final residual from limbs), per set
#define XQW(S, TH0, TH1, TL0, TL1) {                                              \
        const size_t ra = (size_t)(tokenBase + (S) * 16 + m) * DIM + quad * 8;    \
        f32x4 a0 = __builtin_nontemporal_load((const f32x4*)(x + ra));            \
        f32x4 a1 = __builtin_nontemporal_load((const f32x4*)(x + ra + 4));        \
        f32x4 a2 = __builtin_nontemporal_load((const f32x4*)(x + ra + 32));       \
        f32x4 a3 = __builtin_nontemporal_load((const f32x4*)(x + ra + 36));       \
        _Pragma("unroll")                                                         \
        for (int j = 0; j < 4; ++j) {                                             \
            a0[j] -= fmaf(RISCALE, (float)TL0[j],   (float)TH0[j]);               \
            a1[j] -= fmaf(RISCALE, (float)TL0[j+4], (float)TH0[j+4]);             \
            a2[j] -= fmaf(RISCALE, (float)TL1[j],   (float)TH1[j]);               \
            a3[j] -= fmaf(RISCALE, (float)TL1[j+4], (float)TH1[j+4]);             \
        }                                                                         \
        __builtin_nontemporal_store(a0, (f32x4*)(out + ra));                      \
        __builtin_nontemporal_store(a1, (f32x4*)(out + ra + 4));                  \
        __builtin_nontemporal_store(a2, (f32x4*)(out + ra + 32));                 \
        __builtin_nontemporal_store(a3, (f32x4*)(out + ra + 36));                 \
    }
    XQW(0, th00, th01, tl00, tl01);
    XQW(1, th10, th11, tl10, tl11);
    XQW(2, th20, th21, tl20, tl21);
    XQW(3, th30, th31, tl30, tl31);

#undef COMPUTE
#undef STAGE
#undef LOADTOK
#undef REDUCE
#undef RESID
#undef XQW
}

extern "C" void kernel_launch(void* const* d_in, const int* in_sizes, int n_in,
                              void* d_out, int out_size, void* d_ws, size_t ws_size,
                              hipStream_t stream) {
    const float* x   = (const float*)d_in[0];   // (N, D)
    const float* cb  = (const float*)d_in[1];   // (Q, K, D)
    float*       out = (float*)d_out;           // [xq | indices | losses]
    char*        ws  = (char*)d_ws;

    _Float16* G = (_Float16*)ws;   // 256 minis x 8448 B = 2,162,688 B

    hipMemsetAsync(out + (size_t)N_TOK * DIM + (size_t)N_TOK * QS, 0,
                   QS * sizeof(float), stream);

    conv_kernel<<<512, 256, 0, stream>>>(cb, G);
    dc2_kernel<<<(QS * KS + 255) / 256, 256, 0, stream>>>(cb, (float*)ws);
    rvq_mfma_kernel<<<N_TOK / 64, 64, 0, stream>>>(x, cb, G, out);
}